// Round 15
// baseline (311.329 us; speedup 1.0000x reference)
//
#include <hip/hip_runtime.h>
#include <math.h>

#define N_ATOMS 50000
#define E_EDGES 100000
#define B_G     50
#define M_M     50
#define NPG     1000
#define DIN     32
#define H1C     32
#define H2C     64
#define DEC     16
#define AAF     95
#define G_DIM   128
#define K_ST    3
#define T_L     6
#define EA_E    98
#define XDIM    159          // H2 + AAF
#define NS      21           // K + T*K weight slices
#define MPAD    64           // M padded for regular tiling
#define GP      132          // G_DIM padded (fp32 LDS rows)
#define GPS     136          // G_DIM padded (bf16 LDS rows, 272B = 16B-aligned stride)
#define KP2     168          // K padded for bf16 GEMM operands
#define KW      544          // edge-MLP K (512 + 32 bias rows)
#define SLC     10           // atom-scatter slices per graph
#define APB     100          // atoms per slice (NPG / SLC)
#define NSB     ((N_ATOMS + 255) / 256)   // 196 offset blocks

// prep_all linear-work segment offsets
#define OFF_WE2 (H1C * KW)                          // 17408
#define OFF_WT  (OFF_WE2 + H2C * KW)                // 52224
#define OFF_AW  (OFF_WT + NS * XDIM * G_DIM)        // 479616
#define OFF_DEG (OFF_AW + (T_L - 1) * K_ST * G_DIM * G_DIM)  // 725376
#define PREP_TOTAL (OFF_DEG + E_EDGES)              // 825376

typedef __attribute__((ext_vector_type(8))) short bf16x8;
typedef __attribute__((ext_vector_type(4))) float f32x4;
typedef __attribute__((ext_vector_type(4))) unsigned int u32x4;

__device__ __forceinline__ short f2bf(float f) {
    unsigned int u = __float_as_uint(f);
    unsigned int r = (u + 0x7FFFu + ((u >> 16) & 1u)) >> 16;   // RNE
    return (short)r;
}
__device__ __forceinline__ float bf2f(short b) {
    return __uint_as_float(((unsigned int)(unsigned short)b) << 16);
}
// packed fp32->bf16 RNE convert (no builtin on gfx950; asm is scheduler-friendly)
__device__ __forceinline__ unsigned int cvtpk_bf16(float lo, float hi) {
    unsigned int r;
    asm("v_cvt_pk_bf16_f32 %0, %1, %2" : "=v"(r) : "v"(lo), "v"(hi));
    return r;
}

__device__ __forceinline__ void f4fma(float4& d, float s, const float4& v) {
    d.x += s * v.x; d.y += s * v.y; d.z += s * v.z; d.w += s * v.w;
}
__device__ __forceinline__ void f4add(float4& d, const float4& v) {
    d.x += v.x; d.y += v.y; d.z += v.z; d.w += v.w;
}
__device__ __forceinline__ void f4relu(float4& d) {
    d.x = fmaxf(d.x, 0.f); d.y = fmaxf(d.y, 0.f);
    d.z = fmaxf(d.z, 0.f); d.w = fmaxf(d.w, 0.f);
}

// ---------------------------------------------------------------------------
// prep_all: one kernel for all one-time prep (R3 fusion, verified).
// ---------------------------------------------------------------------------
__global__ __launch_bounds__(256) void prep_all(
    const float* __restrict__ We1, const float* __restrict__ be1, short* __restrict__ WB1,
    const float* __restrict__ We2, const float* __restrict__ be2, short* __restrict__ WB2,
    const float* __restrict__ init_w, const float* __restrict__ root_w, short* __restrict__ Wtb,
    const float* __restrict__ arma_w, short* __restrict__ Wab,
    const int* __restrict__ eidx, int* __restrict__ deg,
    const int* __restrict__ aei, int* __restrict__ aa_off,
    int* __restrict__ aa_src, float* __restrict__ aa_nrm)
{
    int tid = threadIdx.x;
    if (blockIdx.x == 0) {
        __shared__ int   sdeg[M_M];
        __shared__ int   scur[M_M];
        __shared__ float sdinv[M_M];
        __shared__ int   soff[M_M + 1];
        if (tid < M_M) { sdeg[tid] = 0; scur[tid] = 0; }
        __syncthreads();
        if (tid < EA_E) atomicAdd(&sdeg[aei[EA_E + tid]], 1);
        __syncthreads();
        if (tid < M_M) {
            float dv = (float)sdeg[tid];
            sdinv[tid] = (dv > 0.f) ? (1.f / sqrtf(fmaxf(dv, 1.f))) : 0.f;
        }
        __syncthreads();
        if (tid == 0) {
            soff[0] = 0;
            for (int m = 0; m < M_M; ++m) soff[m + 1] = soff[m] + sdeg[m];
        }
        __syncthreads();
        if (tid < EA_E) {
            int ss = aei[tid], dd = aei[EA_E + tid];
            int pos = atomicAdd(&scur[dd], 1);
            int idx = soff[dd] + pos;
            aa_src[idx] = ss;
            aa_nrm[idx] = sdinv[ss] * sdinv[dd];
        }
        if (tid < M_M + 1) aa_off[tid] = soff[tid];
        return;
    }
    int idx = (blockIdx.x - 1) * 256 + tid;
    if (idx < OFF_WE2) {
        int o = idx / KW, k = idx - o * KW;
        float v = (k < 512) ? We1[(size_t)k * H1C + o]
                            : be1[(size_t)(k - 512) * H1C + o];
        WB1[idx] = f2bf(v);
    } else if (idx < OFF_WT) {
        int rem = idx - OFF_WE2;
        int o = rem / KW, k = rem - o * KW;
        float v = (k < 512) ? We2[(size_t)k * H2C + o]
                            : be2[(size_t)(k - 512) * H2C + o];
        WB2[rem] = f2bf(v);
    } else if (idx < OFF_AW) {
        int rem = idx - OFF_WT;
        int s = rem / (XDIM * G_DIM);
        int r2 = rem - s * XDIM * G_DIM;
        int k = r2 / G_DIM, n = r2 - k * G_DIM;
        float v = (s < K_ST) ? init_w[rem]
                             : root_w[(size_t)(s - K_ST) * XDIM * G_DIM + r2];
        Wtb[(size_t)s * G_DIM * KP2 + n * KP2 + k] = f2bf(v);
    } else if (idx < OFF_DEG) {
        int rem = idx - OFF_AW;
        int slot = rem / (G_DIM * G_DIM);
        int r2 = rem - slot * G_DIM * G_DIM;
        int p = r2 / G_DIM, n = r2 - p * G_DIM;    // arma_w[slot][p][n]
        Wab[(size_t)slot * G_DIM * G_DIM + n * G_DIM + p] = f2bf(arma_w[rem]);
    } else if (idx < PREP_TOTAL) {
        int e = idx - OFF_DEG;
        atomicAdd(&deg[eidx[E_EDGES + e]], 1);
    }
}

// ---------------------------------------------------------------------------
// csr_offsets (R12, verified): single kernel replaces the 3-phase scan.
// ---------------------------------------------------------------------------
__global__ __launch_bounds__(256) void csr_offsets(const int* __restrict__ deg,
                                                   int* __restrict__ ecnt,
                                                   int* __restrict__ aoff)
{
    __shared__ int tmp[256];
    __shared__ int base_s;
    int tid = threadIdx.x;
    int n = blockIdx.x * 256 + tid;
    int v = (n < N_ATOMS) ? deg[n] : 0;
    tmp[tid] = v;
    __syncthreads();
    for (int off = 1; off < 256; off <<= 1) {
        int t = tmp[tid];
        int add = (tid >= off) ? tmp[tid - off] : 0;
        __syncthreads();
        tmp[tid] = t + add;
        __syncthreads();
    }
    if (tid == 255) base_s = atomicAdd(ecnt, tmp[255]);
    __syncthreads();
    if (n < N_ATOMS) aoff[n] = base_s + tmp[tid] - v;   // exclusive in-block
}

// ---------------------------------------------------------------------------
// Edge message kernel v2 (verified): scatters into dst-sorted CSR slots.
// CIPOS=true (conv1): computes ipos in-kernel; conv2 reads the global copy.
// ---------------------------------------------------------------------------
template<int FOUT, int NTT, int WGRP, int MTB, bool CIPOS>
__global__ __launch_bounds__(256) void edge_msg_v2(
    const float* __restrict__ h, const float* __restrict__ ea,
    const int* __restrict__ eidx, int* __restrict__ ipos,
    const int* __restrict__ off, int* __restrict__ cursor,
    const short* __restrict__ WB, float* __restrict__ msg)
{
    constexpr int KS = 17;                 // 544 / 32
    __shared__ int iplds[MTB * 16];
    int tid  = threadIdx.x;
    int lane = tid & 63, wave = tid >> 6;
    int l16  = lane & 15, quad = lane >> 4;
    int nt   = wave % NTT, tg = wave / NTT;
    int ebase = blockIdx.x * (MTB * 16);

    if (CIPOS) {
        if (tid < MTB * 16) {
            int e = ebase + tid;
            if (e < E_EDGES) {
                int d = eidx[E_EDGES + e];
                int pos = atomicAdd(&cursor[d], 1);
                int p = off[d] + pos;
                iplds[tid] = p;
                ipos[e] = p;
            }
        }
    }

    // B fragments for this wave's n-strip: held in VGPRs for all m-tiles.
    bf16x8 Bfr[KS];
    {
        const short* wb = WB + (size_t)(nt * 16 + l16) * KW;
        #pragma unroll
        for (int ks = 0; ks < KS; ++ks)
            Bfr[ks] = *(const bf16x8*)(wb + ks * 32 + quad * 8);
    }
    if (CIPOS) __syncthreads();

    for (int t = tg; t < MTB; t += WGRP) {
        int e  = ebase + t * 16 + l16;
        int es = (e < E_EDGES) ? e : (E_EDGES - 1);
        int s  = eidx[es];
        float4 h0 = *(const float4*)(h + (size_t)s * 32 + quad * 8);
        float4 h1 = *(const float4*)(h + (size_t)s * 32 + quad * 8 + 4);
        float hf[8] = {h0.x, h0.y, h0.z, h0.w, h1.x, h1.y, h1.z, h1.w};
        float4 e0 = *(const float4*)(ea + (size_t)es * DEC);
        float4 e1 = *(const float4*)(ea + (size_t)es * DEC + 4);
        float4 e2 = *(const float4*)(ea + (size_t)es * DEC + 8);
        float4 e3 = *(const float4*)(ea + (size_t)es * DEC + 12);
        float eaf[16] = {e0.x, e0.y, e0.z, e0.w, e1.x, e1.y, e1.z, e1.w,
                         e2.x, e2.y, e2.z, e2.w, e3.x, e3.y, e3.z, e3.w};

        f32x4 acc = (f32x4){0.f, 0.f, 0.f, 0.f};
        #pragma unroll
        for (int ks = 0; ks < KS; ++ks) {
            u32x4 av;
            if (ks < DEC) {
                float fac = eaf[ks];
                #pragma unroll
                for (int j = 0; j < 4; ++j)
                    av[j] = cvtpk_bf16(fac * hf[2 * j], fac * hf[2 * j + 1]);
            } else {                       // bias block: fac = 1
                #pragma unroll
                for (int j = 0; j < 4; ++j)
                    av[j] = cvtpk_bf16(hf[2 * j], hf[2 * j + 1]);
            }
            bf16x8 a = __builtin_bit_cast(bf16x8, av);
            acc = __builtin_amdgcn_mfma_f32_16x16x32_bf16(a, Bfr[ks], acc, 0, 0, 0);
        }
        // C layout: row = quad*4 + r (edge), col = nt*16 + l16 (out feature)
        int erb = ebase + t * 16 + quad * 4;
        #pragma unroll
        for (int r = 0; r < 4; ++r) {
            int ee = erb + r;
            if (ee < E_EDGES) {
                int p = CIPOS ? iplds[t * 16 + quad * 4 + r] : ipos[ee];
                msg[(size_t)p * FOUT + nt * 16 + l16] = acc[r];
            }
        }
    }
}

// ---------------------------------------------------------------------------
// Gather + node update fused; msg rows CSR-slot ordered -> contiguous reads.
// Node range = [aoff[n], aoff[n]+deg[n]) (atomic-base CSR).
// SCORE=true (conv2, FOUT=64): fused attention score via wave shuffle-reduce.
// ---------------------------------------------------------------------------
template<int FIN, int FOUT, bool SCORE>
__global__ __launch_bounds__(256) void gather_update(
    const float* __restrict__ msg, const int* __restrict__ aoff,
    const int* __restrict__ deg, const float* __restrict__ hin,
    const float* __restrict__ root, const float* __restrict__ bias,
    float* __restrict__ hout,
    const float* __restrict__ wa, const float* __restrict__ ba,
    float* __restrict__ sc)
{
    constexpr int NPB = 256 / FOUT;
    __shared__ float rlds[FIN][FOUT];
    __shared__ float hlds[NPB][FIN];
    int tid = threadIdx.x;
    for (int i = tid; i < FIN * FOUT / 4; i += 256) {
        *(float4*)&rlds[0][i * 4] = *(const float4*)(root + i * 4);
    }
    int nb = blockIdx.x * NPB;
    for (int i = tid; i < NPB * FIN; i += 256) {
        int ln = i / FIN, f = i % FIN;
        int n = nb + ln;
        hlds[ln][f] = (n < N_ATOMS) ? hin[(size_t)n * FIN + f] : 0.f;
    }
    __syncthreads();

    int ln = tid / FOUT, o = tid % FOUT;
    int n = nb + ln;
    if (n >= N_ATOMS) return;
    float acc = bias[o];
    #pragma unroll 8
    for (int f = 0; f < FIN; ++f) acc += hlds[ln][f] * rlds[f][o];
    int j0 = aoff[n], j1 = j0 + deg[n];
    for (int j = j0; j < j1; ++j) {
        acc += msg[(size_t)j * FOUT + o];      // contiguous, coalesced
    }
    float hv = fmaxf(acc, 0.f);
    hout[(size_t)n * FOUT + o] = hv;
    if constexpr (SCORE) {
        static_assert(FOUT == 64, "score fusion needs node==wave");
        float sv = hv * wa[o];
        #pragma unroll
        for (int d = 32; d > 0; d >>= 1) sv += __shfl_down(sv, d);
        if (o == 0) sc[n] = sv + ba[0];
    }
}

// ---------------------------------------------------------------------------
// Atom scatter with inline softmax (R14 prefetch variant, verified neutral).
// ---------------------------------------------------------------------------
__global__ __launch_bounds__(256, 1) void atom_scatter_sm(
    const float* __restrict__ h2, const float* __restrict__ sc,
    const int* __restrict__ labels, float* __restrict__ partial)
{
    __shared__ float aa4[4][M_M][H2C];   // 51.2 KB
    __shared__ float red[256];
    int b = blockIdx.x / SLC, s = blockIdx.x % SLC;
    int tid = threadIdx.x;
    int wave = tid >> 6, lane = tid & 63;
    const float* sb = sc + (size_t)b * NPG;

    for (int i = tid; i < 4 * M_M * H2C; i += 256) ((float*)aa4)[i] = 0.f;

    float lmax = -1e30f;
    for (int n = tid; n < NPG; n += 256) lmax = fmaxf(lmax, sb[n]);
    red[tid] = lmax;
    __syncthreads();
    for (int off = 128; off > 0; off >>= 1) {
        if (tid < off) red[tid] = fmaxf(red[tid], red[tid + off]);
        __syncthreads();
    }
    float mx = red[0];
    __syncthreads();
    float lsum = 0.f;
    for (int n = tid; n < NPG; n += 256) lsum += expf(sb[n] - mx);
    red[tid] = lsum;
    __syncthreads();
    for (int off = 128; off > 0; off >>= 1) {
        if (tid < off) red[tid] += red[tid + off];
        __syncthreads();
    }
    float inv = 1.f / red[0];
    __syncthreads();

    int nbase = s * APB;
    const float* hb = h2 + (size_t)b * NPG * H2C;
    int   lbls[APB / 4];
    float wts[APB / 4];
    float hvs[APB / 4];
    #pragma unroll
    for (int it = 0; it < APB / 4; ++it) {
        int n = nbase + it * 4 + wave;               // wave-uniform
        lbls[it] = labels[b * NPG + n];
        wts[it]  = expf(sb[n] - mx) * inv;
        hvs[it]  = hb[(size_t)n * H2C + lane];       // 256B coalesced per wave
    }
    #pragma unroll
    for (int it = 0; it < APB / 4; ++it) {
        aa4[wave][lbls[it]][lane] += hvs[it] * wts[it];   // identical order
    }
    __syncthreads();
    float* pb = partial + (size_t)(b * SLC + s) * M_M * H2C;
    for (int i = tid; i < M_M * H2C; i += 256) {
        float v = ((float*)aa4)[i] + ((float*)aa4)[M_M * H2C + i]
                + ((float*)aa4)[2 * M_M * H2C + i] + ((float*)aa4)[3 * M_M * H2C + i];
        pb[i] = v;
    }
}

// ---------------------------------------------------------------------------
// ARMA recurrence, one block per (b,k), 256 threads (R11, verified <41us).
// R15: x0_finalize folded into the prologue. Each block reduces the 10
// scatter partials for its graph in the IDENTICAL s=0..9 order (+aaf, f2bf)
// into an LDS staging buffer (cast into Rall[0..1], free until root GEMMs),
// loads its A-fragments from there, then the GEMMs overwrite it. Bit-
// identical x0 values; x0b global round-trip + 1 dispatch eliminated.
// ---------------------------------------------------------------------------
__global__ __launch_bounds__(256, 1) void arma_iter(
    const float* __restrict__ partial, const float* __restrict__ aaf,
    const short* __restrict__ Wtb,
    const short* __restrict__ Wab, const float* __restrict__ arma_bias,
    const int* __restrict__ aa_off, const int* __restrict__ aa_src,
    const float* __restrict__ aa_nrm, float* __restrict__ gfull)
{
    __shared__ float Abuf[MPAD][GP];        // 33.8 KB (propagated-state input)
    __shared__ float Rall[3][MPAD][GP];     // 101.4 KB (x0 staging, then roots)
    __shared__ short Bb16[MPAD][GPS];       // 17.4 KB (bf16 state shadow)
    __shared__ int   s_off[M_M + 1];
    __shared__ int   s_src[EA_E];
    __shared__ float s_nrm[EA_E];
    int b = blockIdx.x / K_ST, k = blockIdx.x % K_ST;
    int tid = threadIdx.x;
    int oi = tid & 15, mi = tid >> 4;       // prop: mi in [0,16), 4 rows each
    int c0 = oi * 4, c1 = 64 + oi * 4;
    int lane = tid & 63, wave = tid >> 6;   // 4 waves
    int l16 = lane & 15, quad = lane >> 4;
    int w2 = wave >> 1, nh = wave & 1;      // wave handles m-tiles {w2, w2+2}

    if (tid < M_M + 1) s_off[tid] = aa_off[tid];
    if (tid < EA_E) { s_src[tid] = aa_src[tid]; s_nrm[tid] = aa_nrm[tid]; }
    for (int i = tid; i < MPAD * GPS / 2; i += 256) {
        ((int*)Bb16)[i] = 0;           // zero bf16 shadow (rows >= M_M stay 0)
    }

    // ---- fused x0_finalize: reduce partials -> bf16 x0 rows in LDS --------
    short* Xl = (short*)&Rall[0][0][0];    // 64*168 shorts = 43 KB < Rall[0..1]
    {
        const float* pbase = partial + (size_t)b * SLC * M_M * H2C;
        for (int i = tid; i < MPAD * KP2; i += 256) {
            int m = i / KP2, kk = i - m * KP2;
            float v = 0.f;
            if (m < M_M) {
                if (kk < H2C) {
                    const float* pp = pbase + m * H2C + kk;
                    #pragma unroll
                    for (int ss = 0; ss < SLC; ++ss) v += pp[(size_t)ss * (M_M * H2C)];
                } else if (kk < XDIM) {
                    v = aaf[((size_t)b * M_M + m) * AAF + (kk - H2C)];
                }
            }
            Xl[i] = f2bf(v);
        }
    }
    __syncthreads();   // Xl complete

    // A-fragments for this wave's 2 m-tiles (32 x0 rows), reused by 7 GEMMs.
    bf16x8 Afr[2][5];
    #pragma unroll
    for (int h = 0; h < 2; ++h) {
        int mt = w2 + 2 * h;
        const short* xb = Xl + (size_t)(mt * 16 + l16) * KP2;
        #pragma unroll
        for (int ks = 0; ks < 5; ++ks)
            Afr[h][ks] = *(const bf16x8*)(xb + ks * 32 + quad * 8);
    }
    __syncthreads();   // all Afr reads done before Rall is overwritten

    // x0 @ Wtb[slice] -> dst in LDS. One shared B-frag set, 2 m-tiles.
    auto x0_gemm = [&](const short* __restrict__ W, float (*dst)[GP]) {
        bf16x8 Bfr[5][4];
        #pragma unroll
        for (int ks = 0; ks < 5; ++ks)
            #pragma unroll
            for (int nt = 0; nt < 4; ++nt)
                Bfr[ks][nt] = *(const bf16x8*)(W +
                    (size_t)((nh * 4 + nt) * 16 + l16) * KP2 + ks * 32 + quad * 8);
        #pragma unroll
        for (int h = 0; h < 2; ++h) {
            int mt = w2 + 2 * h;
            f32x4 acc[4];
            #pragma unroll
            for (int nt = 0; nt < 4; ++nt) acc[nt] = (f32x4){0.f, 0.f, 0.f, 0.f};
            #pragma unroll
            for (int ks = 0; ks < 5; ++ks)
                #pragma unroll
                for (int nt = 0; nt < 4; ++nt)
                    acc[nt] = __builtin_amdgcn_mfma_f32_16x16x32_bf16(
                        Afr[h][ks], Bfr[ks][nt], acc[nt], 0, 0, 0);
            #pragma unroll
            for (int nt = 0; nt < 4; ++nt)
                #pragma unroll
                for (int r = 0; r < 4; ++r)
                    dst[mt * 16 + quad * 4 + r][(nh * 4 + nt) * 16 + l16] = acc[nt][r];
        }
    };

    // prologue: init GEMM -> Abuf; root GEMMs t=0..2 -> Rall[0..2]
    x0_gemm(Wtb + (size_t)k * G_DIM * KP2, Abuf);
    #pragma unroll
    for (int t = 0; t < 3; ++t)
        x0_gemm(Wtb + (size_t)(K_ST + t * K_ST + k) * G_DIM * KP2, Rall[t]);

    float* gb = gfull + ((size_t)(b * K_ST + k)) * M_M * G_DIM;
    __syncthreads();   // Abuf(init) + Rall(0..2) + Bb16(zero) + CSR visible

    #pragma unroll
    for (int t = 0; t < T_L; ++t) {
        if (t > 0) {
            // state GEMM: relu-state (bf16 shadow) @ Wab -> Abuf.
            // Shared W-frag set (16 loads) feeds both m-tiles (32 MFMAs).
            const short* aw = Wab + (size_t)((t - 1) * K_ST + k) * G_DIM * G_DIM;
            bf16x8 Wfr[4][4];
            #pragma unroll
            for (int ks = 0; ks < 4; ++ks)
                #pragma unroll
                for (int nt = 0; nt < 4; ++nt)
                    Wfr[ks][nt] = *(const bf16x8*)(aw +
                        (size_t)((nh * 4 + nt) * 16 + l16) * G_DIM + ks * 32 + quad * 8);
            #pragma unroll
            for (int h = 0; h < 2; ++h) {
                int mt = w2 + 2 * h;
                f32x4 acc[4];
                #pragma unroll
                for (int nt = 0; nt < 4; ++nt) acc[nt] = (f32x4){0.f, 0.f, 0.f, 0.f};
                #pragma unroll
                for (int ks = 0; ks < 4; ++ks) {
                    bf16x8 a = *(const bf16x8*)&Bb16[mt * 16 + l16][ks * 32 + quad * 8];
                    #pragma unroll
                    for (int nt = 0; nt < 4; ++nt)
                        acc[nt] = __builtin_amdgcn_mfma_f32_16x16x32_bf16(
                            a, Wfr[ks][nt], acc[nt], 0, 0, 0);
                }
                #pragma unroll
                for (int nt = 0; nt < 4; ++nt)
                    #pragma unroll
                    for (int r = 0; r < 4; ++r)
                        Abuf[mt * 16 + quad * 4 + r][(nh * 4 + nt) * 16 + l16] = acc[nt][r];
            }
            if (t == 3) {
                // batch root GEMMs t=3..5 into Rall[0..2] (old contents'
                // consumers finished before the end-of-step-2 barrier)
                #pragma unroll
                for (int tt = 3; tt < 6; ++tt)
                    x0_gemm(Wtb + (size_t)(K_ST + tt * K_ST + k) * G_DIM * KP2,
                            Rall[tt - 3]);
            }
            __syncthreads();   // Abuf (+Rall at t==3) complete before prop
        }
        const float (*Rb)[GP] = Rall[t % 3];
        const float* bb = arma_bias + ((size_t)t * K_ST + k) * G_DIM;
        float4 bias0 = *(const float4*)(bb + c0);
        float4 bias1 = *(const float4*)(bb + c1);
        #pragma unroll
        for (int r = 0; r < 4; ++r) {
            int m = mi * 4 + r;
            if (m < M_M) {
                float4 v0 = bias0, v1 = bias1;
                f4add(v0, *(const float4*)&Rb[m][c0]);
                f4add(v1, *(const float4*)&Rb[m][c1]);
                int j0 = s_off[m], j1 = s_off[m + 1];
                for (int j = j0; j < j1; ++j) {
                    float nv = s_nrm[j];
                    const float* ap = &Abuf[s_src[j]][0];
                    f4fma(v0, nv, *(const float4*)(ap + c0));
                    f4fma(v1, nv, *(const float4*)(ap + c1));
                }
                f4relu(v0);
                f4relu(v1);
                unsigned int p0 = cvtpk_bf16(v0.x, v0.y);
                unsigned int p1 = cvtpk_bf16(v0.z, v0.w);
                unsigned int p2 = cvtpk_bf16(v1.x, v1.y);
                unsigned int p3 = cvtpk_bf16(v1.z, v1.w);
                *(uint2*)&Bb16[m][c0] = make_uint2(p0, p1);
                *(uint2*)&Bb16[m][c1] = make_uint2(p2, p3);
                if (t == T_L - 1) {
                    *(float4*)(gb + m * G_DIM + c0) = v0;
                    *(float4*)(gb + m * G_DIM + c1) = v1;
                }
            }
        }
        __syncthreads();   // state complete; Abuf/Rall reads done
    }
}

// ---------------------------------------------------------------------------
// Mean over K, amino attention readout, MLP head. One block per graph.
// ---------------------------------------------------------------------------
__global__ __launch_bounds__(128) void aa_readout_mlp(
    const float* __restrict__ gfull, const float* __restrict__ wa,
    const float* __restrict__ ba,
    const float* __restrict__ W1, const float* __restrict__ b1,
    const float* __restrict__ W2, const float* __restrict__ b2,
    const float* __restrict__ W3, const float* __restrict__ b3,
    const float* __restrict__ W4, const float* __restrict__ b4,
    float* __restrict__ out)
{
    __shared__ float g[M_M][G_DIM + 1];
    __shared__ float s2[M_M];
    __shared__ float p[G_DIM];
    __shared__ float r1[64], r2[32], r3[16];
    int b = blockIdx.x, tid = threadIdx.x;
    const float* g0 = gfull + (size_t)b * K_ST * M_M * G_DIM;
    for (int i = tid; i < M_M * G_DIM; i += 128) {
        int m = i >> 7, o = i & 127;
        g[m][o] = (g0[i] + g0[M_M*G_DIM + i] + g0[2*M_M*G_DIM + i]) * (1.f/3.f);
    }
    __syncthreads();
    if (tid < M_M) {
        float sv = ba[0];
        for (int o = 0; o < G_DIM; ++o) sv += g[tid][o] * wa[o];
        s2[tid] = sv;
    }
    __syncthreads();
    if (tid < 64) {
        float v = (tid < M_M) ? s2[tid] : -1e30f;
        float mx = v;
        #pragma unroll
        for (int d = 32; d > 0; d >>= 1) mx = fmaxf(mx, __shfl_xor(mx, d));
        float e = (tid < M_M) ? expf(s2[tid] - mx) : 0.f;
        float den = e;
        #pragma unroll
        for (int d = 32; d > 0; d >>= 1) den += __shfl_xor(den, d);
        float inv = 1.f / den;
        if (tid < M_M) s2[tid] = e * inv;
    }
    __syncthreads();
    {
        float pv = 0.f;
        for (int m = 0; m < M_M; ++m) pv += g[m][tid] * s2[m];
        p[tid] = pv;
    }
    __syncthreads();
    if (tid < 64) {
        float v = b1[tid];
        for (int i = 0; i < 128; ++i) v += p[i] * W1[i * 64 + tid];
        r1[tid] = fmaxf(v, 0.f);
    }
    __syncthreads();
    if (tid < 32) {
        float v = b2[tid];
        for (int i = 0; i < 64; ++i) v += r1[i] * W2[i * 32 + tid];
        r2[tid] = fmaxf(v, 0.f);
    }
    __syncthreads();
    if (tid < 16) {
        float v = b3[tid];
        for (int i = 0; i < 32; ++i) v += r2[i] * W3[i * 16 + tid];
        r3[tid] = fmaxf(v, 0.f);
    }
    __syncthreads();
    if (tid == 0) {
        float v = b4[0];
        for (int i = 0; i < 16; ++i) v += r3[i] * W4[i];
        out[b] = v;
    }
}

// ---------------------------------------------------------------------------
extern "C" void kernel_launch(void* const* d_in, const int* in_sizes, int n_in,
                              void* d_out, int out_size, void* d_ws, size_t ws_size,
                              hipStream_t stream)
{
    (void)in_sizes; (void)n_in; (void)out_size; (void)ws_size;
    const float* x            = (const float*)d_in[0];
    const float* edge_attr    = (const float*)d_in[1];
    const float* aa_features  = (const float*)d_in[2];
    const int*   edge_index   = (const int*)  d_in[3];
    const int*   mono_labels  = (const int*)  d_in[4];
    const int*   amino_ei     = (const int*)  d_in[5];
    const float* W_e1 = (const float*)d_in[6];
    const float* b_e1 = (const float*)d_in[7];
    const float* root1= (const float*)d_in[8];
    const float* bias1= (const float*)d_in[9];
    const float* W_e2 = (const float*)d_in[10];
    const float* b_e2 = (const float*)d_in[11];
    const float* root2= (const float*)d_in[12];
    const float* bias2= (const float*)d_in[13];
    const float* Wa_atom = (const float*)d_in[14];
    const float* ba_atom = (const float*)d_in[15];
    const float* arma_init_w = (const float*)d_in[16];
    const float* arma_w      = (const float*)d_in[17];
    const float* arma_root_w = (const float*)d_in[18];
    const float* arma_bias   = (const float*)d_in[19];
    const float* Wa_aa = (const float*)d_in[20];
    const float* ba_aa = (const float*)d_in[21];
    const float* W1 = (const float*)d_in[22];
    const float* b1 = (const float*)d_in[23];
    const float* W2 = (const float*)d_in[24];
    const float* b2 = (const float*)d_in[25];
    const float* W3 = (const float*)d_in[26];
    const float* b3 = (const float*)d_in[27];
    const float* W4 = (const float*)d_in[28];
    const float* b4 = (const float*)d_in[29];

    float* ws = (float*)d_ws;
    float* h1    = ws;                                   // N*32
    float* h2    = h1   + (size_t)N_ATOMS * H1C;         // N*64
    float* h_aa  = h2   + (size_t)N_ATOMS * H2C;         // legacy slot, unused
    float* sc    = h_aa + (size_t)B_G * M_M * XDIM;      // B*NPG raw scores
    int*   aa_off = (int*)(sc + (size_t)B_G * NPG);      // M+1
    int*   aa_src = aa_off + (M_M + 1);                  // EA
    float* aa_nrm = (float*)(aa_src + EA_E);             // EA
    int*   deg    = (int*)(aa_nrm + EA_E);               // N+1 (counts)
    int*   cursor = deg + (N_ATOMS + 1);                 // N
    int*   ecnt   = cursor + N_ATOMS;                    // 1 (CSR base counter)
    int*   gcnt   = ecnt + 1;                            // B_G (unused, layout keep)
    int*   ipos   = gcnt + B_G;                          // E (edge -> CSR slot)
    int*   aoff   = ipos + E_EDGES;                      // N (node slot bases)
    float* RC    = (float*)(aoff + N_ATOMS);             // msg/partial arena
    float* gfull = RC + (size_t)B_G * NS * M_M * G_DIM;  // B*3*M*128
    short* Wtb   = (short*)((((uintptr_t)(gfull + (size_t)B_G * K_ST * M_M * G_DIM)) + 15)
                            & ~(uintptr_t)15);           // NS*128*168 bf16 (903 KB)
    short* x0b   = Wtb + (size_t)NS * G_DIM * KP2;       // legacy slot (layout keep)
    short* Wab   = x0b + (size_t)B_G * MPAD * KP2;       // 15*128*128 bf16 (492 KB)
    short* WB1   = Wab + (size_t)(T_L - 1) * K_ST * G_DIM * G_DIM; // 32*544 bf16
    short* WB2   = WB1 + (size_t)H1C * KW;               // 64*544 bf16
    float* msg   = RC;     // edge messages (dst-sorted)
    float* partial = RC;   // scatter partials (6.4 MB), msg dead by then
    (void)h_aa; (void)x0b;

    // zero: deg(N+1) + cursor(N) + ecnt(1) + gcnt(B_G)
    (void)hipMemsetAsync(deg, 0, (2 * N_ATOMS + 2 + B_G) * sizeof(int), stream);

    // all one-time prep (bf16 packs + deg count + amino CSR) in one kernel
    prep_all<<<1 + (PREP_TOTAL + 255) / 256, 256, 0, stream>>>(
        W_e1, b_e1, WB1, W_e2, b_e2, WB2,
        arma_init_w, arma_root_w, Wtb, arma_w, Wab,
        edge_index, deg, amino_ei, aa_off, aa_src, aa_nrm);

    // CSR offsets: single atomic-base kernel (replaces 3-phase scan)
    csr_offsets<<<NSB, 256, 0, stream>>>(deg, ecnt, aoff);

    // conv1 (MFMA): 128 edges/block; computes ipos in-kernel, scatters to slots
    edge_msg_v2<H1C, 2, 2, 8, true><<<(E_EDGES + 127) / 128, 256, 0, stream>>>(
        x, edge_attr, edge_index, ipos, aoff, cursor, WB1, msg);
    gather_update<DIN, H1C, false><<<(N_ATOMS + 7) / 8, 256, 0, stream>>>(
        msg, aoff, deg, x, root1, bias1, h1, nullptr, nullptr, nullptr);
    // conv2 (MFMA): 128 edges/block; gather fused with attention score
    edge_msg_v2<H2C, 4, 1, 8, false><<<(E_EDGES + 127) / 128, 256, 0, stream>>>(
        h1, edge_attr, edge_index, ipos, nullptr, nullptr, WB2, msg);
    gather_update<H1C, H2C, true><<<(N_ATOMS + 3) / 4, 256, 0, stream>>>(
        msg, aoff, deg, h1, root2, bias2, h2, Wa_atom, ba_atom, sc);

    // atom attention readout: scatter with inline softmax
    atom_scatter_sm<<<B_G * SLC, 256, 0, stream>>>(h2, sc, mono_labels, partial);

    // ARMA: x0 finalize fused into the prologue (reads partials directly)
    arma_iter<<<B_G * K_ST, 256, 0, stream>>>(partial, aa_features, Wtb, Wab,
                                              arma_bias, aa_off, aa_src, aa_nrm,
                                              gfull);
    aa_readout_mlp<<<B_G, 128, 0, stream>>>(gfull, Wa_aa, ba_aa, W1, b1, W2, b2, W3, b3, W4, b4,
                                            (float*)d_out);
}

// Round 16
// 293.520 us; speedup vs baseline: 1.0607x; 1.0607x over previous
//
#include <hip/hip_runtime.h>
#include <math.h>

#define N_ATOMS 50000
#define E_EDGES 100000
#define B_G     50
#define M_M     50
#define NPG     1000
#define DIN     32
#define H1C     32
#define H2C     64
#define DEC     16
#define AAF     95
#define G_DIM   128
#define K_ST    3
#define T_L     6
#define EA_E    98
#define XDIM    159          // H2 + AAF
#define NS      21           // K + T*K weight slices
#define MPAD    64           // M padded for regular tiling
#define GP      132          // G_DIM padded (fp32 LDS rows)
#define GPS     136          // G_DIM padded (bf16 LDS rows, 272B = 16B-aligned stride)
#define KP2     168          // K padded for bf16 GEMM operands
#define KW      544          // edge-MLP K (512 + 32 bias rows)
#define SLC     10           // atom-scatter slices per graph
#define APB     100          // atoms per slice (NPG / SLC)
#define NSB     ((N_ATOMS + 255) / 256)   // 196 offset blocks

// prep_all linear-work segment offsets
#define OFF_WE2 (H1C * KW)                          // 17408
#define OFF_WT  (OFF_WE2 + H2C * KW)                // 52224
#define OFF_AW  (OFF_WT + NS * XDIM * G_DIM)        // 479616
#define OFF_DEG (OFF_AW + (T_L - 1) * K_ST * G_DIM * G_DIM)  // 725376
#define PREP_TOTAL (OFF_DEG + E_EDGES)              // 825376

typedef __attribute__((ext_vector_type(8))) short bf16x8;
typedef __attribute__((ext_vector_type(4))) float f32x4;
typedef __attribute__((ext_vector_type(4))) unsigned int u32x4;

__device__ __forceinline__ short f2bf(float f) {
    unsigned int u = __float_as_uint(f);
    unsigned int r = (u + 0x7FFFu + ((u >> 16) & 1u)) >> 16;   // RNE
    return (short)r;
}
__device__ __forceinline__ float bf2f(short b) {
    return __uint_as_float(((unsigned int)(unsigned short)b) << 16);
}
// packed fp32->bf16 RNE convert (no builtin on gfx950; asm is scheduler-friendly)
__device__ __forceinline__ unsigned int cvtpk_bf16(float lo, float hi) {
    unsigned int r;
    asm("v_cvt_pk_bf16_f32 %0, %1, %2" : "=v"(r) : "v"(lo), "v"(hi));
    return r;
}

__device__ __forceinline__ void f4fma(float4& d, float s, const float4& v) {
    d.x += s * v.x; d.y += s * v.y; d.z += s * v.z; d.w += s * v.w;
}
__device__ __forceinline__ void f4add(float4& d, const float4& v) {
    d.x += v.x; d.y += v.y; d.z += v.z; d.w += v.w;
}
__device__ __forceinline__ void f4relu(float4& d) {
    d.x = fmaxf(d.x, 0.f); d.y = fmaxf(d.y, 0.f);
    d.z = fmaxf(d.z, 0.f); d.w = fmaxf(d.w, 0.f);
}

// ---------------------------------------------------------------------------
// prep_all: one kernel for all one-time prep (R3 fusion, verified).
// ---------------------------------------------------------------------------
__global__ __launch_bounds__(256) void prep_all(
    const float* __restrict__ We1, const float* __restrict__ be1, short* __restrict__ WB1,
    const float* __restrict__ We2, const float* __restrict__ be2, short* __restrict__ WB2,
    const float* __restrict__ init_w, const float* __restrict__ root_w, short* __restrict__ Wtb,
    const float* __restrict__ arma_w, short* __restrict__ Wab,
    const int* __restrict__ eidx, int* __restrict__ deg,
    const int* __restrict__ aei, int* __restrict__ aa_off,
    int* __restrict__ aa_src, float* __restrict__ aa_nrm)
{
    int tid = threadIdx.x;
    if (blockIdx.x == 0) {
        __shared__ int   sdeg[M_M];
        __shared__ int   scur[M_M];
        __shared__ float sdinv[M_M];
        __shared__ int   soff[M_M + 1];
        if (tid < M_M) { sdeg[tid] = 0; scur[tid] = 0; }
        __syncthreads();
        if (tid < EA_E) atomicAdd(&sdeg[aei[EA_E + tid]], 1);
        __syncthreads();
        if (tid < M_M) {
            float dv = (float)sdeg[tid];
            sdinv[tid] = (dv > 0.f) ? (1.f / sqrtf(fmaxf(dv, 1.f))) : 0.f;
        }
        __syncthreads();
        if (tid == 0) {
            soff[0] = 0;
            for (int m = 0; m < M_M; ++m) soff[m + 1] = soff[m] + sdeg[m];
        }
        __syncthreads();
        if (tid < EA_E) {
            int ss = aei[tid], dd = aei[EA_E + tid];
            int pos = atomicAdd(&scur[dd], 1);
            int idx = soff[dd] + pos;
            aa_src[idx] = ss;
            aa_nrm[idx] = sdinv[ss] * sdinv[dd];
        }
        if (tid < M_M + 1) aa_off[tid] = soff[tid];
        return;
    }
    int idx = (blockIdx.x - 1) * 256 + tid;
    if (idx < OFF_WE2) {
        int o = idx / KW, k = idx - o * KW;
        float v = (k < 512) ? We1[(size_t)k * H1C + o]
                            : be1[(size_t)(k - 512) * H1C + o];
        WB1[idx] = f2bf(v);
    } else if (idx < OFF_WT) {
        int rem = idx - OFF_WE2;
        int o = rem / KW, k = rem - o * KW;
        float v = (k < 512) ? We2[(size_t)k * H2C + o]
                            : be2[(size_t)(k - 512) * H2C + o];
        WB2[rem] = f2bf(v);
    } else if (idx < OFF_AW) {
        int rem = idx - OFF_WT;
        int s = rem / (XDIM * G_DIM);
        int r2 = rem - s * XDIM * G_DIM;
        int k = r2 / G_DIM, n = r2 - k * G_DIM;
        float v = (s < K_ST) ? init_w[rem]
                             : root_w[(size_t)(s - K_ST) * XDIM * G_DIM + r2];
        Wtb[(size_t)s * G_DIM * KP2 + n * KP2 + k] = f2bf(v);
    } else if (idx < OFF_DEG) {
        int rem = idx - OFF_AW;
        int slot = rem / (G_DIM * G_DIM);
        int r2 = rem - slot * G_DIM * G_DIM;
        int p = r2 / G_DIM, n = r2 - p * G_DIM;    // arma_w[slot][p][n]
        Wab[(size_t)slot * G_DIM * G_DIM + n * G_DIM + p] = f2bf(arma_w[rem]);
    } else if (idx < PREP_TOTAL) {
        int e = idx - OFF_DEG;
        atomicAdd(&deg[eidx[E_EDGES + e]], 1);
    }
}

// ---------------------------------------------------------------------------
// csr_offsets (R12, verified): single kernel replaces the 3-phase scan.
// ---------------------------------------------------------------------------
__global__ __launch_bounds__(256) void csr_offsets(const int* __restrict__ deg,
                                                   int* __restrict__ ecnt,
                                                   int* __restrict__ aoff)
{
    __shared__ int tmp[256];
    __shared__ int base_s;
    int tid = threadIdx.x;
    int n = blockIdx.x * 256 + tid;
    int v = (n < N_ATOMS) ? deg[n] : 0;
    tmp[tid] = v;
    __syncthreads();
    for (int off = 1; off < 256; off <<= 1) {
        int t = tmp[tid];
        int add = (tid >= off) ? tmp[tid - off] : 0;
        __syncthreads();
        tmp[tid] = t + add;
        __syncthreads();
    }
    if (tid == 255) base_s = atomicAdd(ecnt, tmp[255]);
    __syncthreads();
    if (n < N_ATOMS) aoff[n] = base_s + tmp[tid] - v;   // exclusive in-block
}

// ---------------------------------------------------------------------------
// Edge message kernel v2 (verified): scatters into dst-sorted CSR slots.
// CIPOS=true (conv1): computes ipos in-kernel; conv2 reads the global copy.
// ---------------------------------------------------------------------------
template<int FOUT, int NTT, int WGRP, int MTB, bool CIPOS>
__global__ __launch_bounds__(256) void edge_msg_v2(
    const float* __restrict__ h, const float* __restrict__ ea,
    const int* __restrict__ eidx, int* __restrict__ ipos,
    const int* __restrict__ off, int* __restrict__ cursor,
    const short* __restrict__ WB, float* __restrict__ msg)
{
    constexpr int KS = 17;                 // 544 / 32
    __shared__ int iplds[MTB * 16];
    int tid  = threadIdx.x;
    int lane = tid & 63, wave = tid >> 6;
    int l16  = lane & 15, quad = lane >> 4;
    int nt   = wave % NTT, tg = wave / NTT;
    int ebase = blockIdx.x * (MTB * 16);

    if (CIPOS) {
        if (tid < MTB * 16) {
            int e = ebase + tid;
            if (e < E_EDGES) {
                int d = eidx[E_EDGES + e];
                int pos = atomicAdd(&cursor[d], 1);
                int p = off[d] + pos;
                iplds[tid] = p;
                ipos[e] = p;
            }
        }
    }

    // B fragments for this wave's n-strip: held in VGPRs for all m-tiles.
    bf16x8 Bfr[KS];
    {
        const short* wb = WB + (size_t)(nt * 16 + l16) * KW;
        #pragma unroll
        for (int ks = 0; ks < KS; ++ks)
            Bfr[ks] = *(const bf16x8*)(wb + ks * 32 + quad * 8);
    }
    if (CIPOS) __syncthreads();

    for (int t = tg; t < MTB; t += WGRP) {
        int e  = ebase + t * 16 + l16;
        int es = (e < E_EDGES) ? e : (E_EDGES - 1);
        int s  = eidx[es];
        float4 h0 = *(const float4*)(h + (size_t)s * 32 + quad * 8);
        float4 h1 = *(const float4*)(h + (size_t)s * 32 + quad * 8 + 4);
        float hf[8] = {h0.x, h0.y, h0.z, h0.w, h1.x, h1.y, h1.z, h1.w};
        float4 e0 = *(const float4*)(ea + (size_t)es * DEC);
        float4 e1 = *(const float4*)(ea + (size_t)es * DEC + 4);
        float4 e2 = *(const float4*)(ea + (size_t)es * DEC + 8);
        float4 e3 = *(const float4*)(ea + (size_t)es * DEC + 12);
        float eaf[16] = {e0.x, e0.y, e0.z, e0.w, e1.x, e1.y, e1.z, e1.w,
                         e2.x, e2.y, e2.z, e2.w, e3.x, e3.y, e3.z, e3.w};

        f32x4 acc = (f32x4){0.f, 0.f, 0.f, 0.f};
        #pragma unroll
        for (int ks = 0; ks < KS; ++ks) {
            u32x4 av;
            if (ks < DEC) {
                float fac = eaf[ks];
                #pragma unroll
                for (int j = 0; j < 4; ++j)
                    av[j] = cvtpk_bf16(fac * hf[2 * j], fac * hf[2 * j + 1]);
            } else {                       // bias block: fac = 1
                #pragma unroll
                for (int j = 0; j < 4; ++j)
                    av[j] = cvtpk_bf16(hf[2 * j], hf[2 * j + 1]);
            }
            bf16x8 a = __builtin_bit_cast(bf16x8, av);
            acc = __builtin_amdgcn_mfma_f32_16x16x32_bf16(a, Bfr[ks], acc, 0, 0, 0);
        }
        // C layout: row = quad*4 + r (edge), col = nt*16 + l16 (out feature)
        int erb = ebase + t * 16 + quad * 4;
        #pragma unroll
        for (int r = 0; r < 4; ++r) {
            int ee = erb + r;
            if (ee < E_EDGES) {
                int p = CIPOS ? iplds[t * 16 + quad * 4 + r] : ipos[ee];
                msg[(size_t)p * FOUT + nt * 16 + l16] = acc[r];
            }
        }
    }
}

// ---------------------------------------------------------------------------
// Gather + node update fused; msg rows CSR-slot ordered -> contiguous reads.
// Node range = [aoff[n], aoff[n]+deg[n]) (atomic-base CSR).
// SCORE=true (conv2, FOUT=64): fused attention score via wave shuffle-reduce.
// ---------------------------------------------------------------------------
template<int FIN, int FOUT, bool SCORE>
__global__ __launch_bounds__(256) void gather_update(
    const float* __restrict__ msg, const int* __restrict__ aoff,
    const int* __restrict__ deg, const float* __restrict__ hin,
    const float* __restrict__ root, const float* __restrict__ bias,
    float* __restrict__ hout,
    const float* __restrict__ wa, const float* __restrict__ ba,
    float* __restrict__ sc)
{
    constexpr int NPB = 256 / FOUT;
    __shared__ float rlds[FIN][FOUT];
    __shared__ float hlds[NPB][FIN];
    int tid = threadIdx.x;
    for (int i = tid; i < FIN * FOUT / 4; i += 256) {
        *(float4*)&rlds[0][i * 4] = *(const float4*)(root + i * 4);
    }
    int nb = blockIdx.x * NPB;
    for (int i = tid; i < NPB * FIN; i += 256) {
        int ln = i / FIN, f = i % FIN;
        int n = nb + ln;
        hlds[ln][f] = (n < N_ATOMS) ? hin[(size_t)n * FIN + f] : 0.f;
    }
    __syncthreads();

    int ln = tid / FOUT, o = tid % FOUT;
    int n = nb + ln;
    if (n >= N_ATOMS) return;
    float acc = bias[o];
    #pragma unroll 8
    for (int f = 0; f < FIN; ++f) acc += hlds[ln][f] * rlds[f][o];
    int j0 = aoff[n], j1 = j0 + deg[n];
    for (int j = j0; j < j1; ++j) {
        acc += msg[(size_t)j * FOUT + o];      // contiguous, coalesced
    }
    float hv = fmaxf(acc, 0.f);
    hout[(size_t)n * FOUT + o] = hv;
    if constexpr (SCORE) {
        static_assert(FOUT == 64, "score fusion needs node==wave");
        float sv = hv * wa[o];
        #pragma unroll
        for (int d = 32; d > 0; d >>= 1) sv += __shfl_down(sv, d);
        if (o == 0) sc[n] = sv + ba[0];
    }
}

// ---------------------------------------------------------------------------
// Atom scatter with inline softmax (R14 prefetch variant, verified neutral).
// ---------------------------------------------------------------------------
__global__ __launch_bounds__(256, 1) void atom_scatter_sm(
    const float* __restrict__ h2, const float* __restrict__ sc,
    const int* __restrict__ labels, float* __restrict__ partial)
{
    __shared__ float aa4[4][M_M][H2C];   // 51.2 KB
    __shared__ float red[256];
    int b = blockIdx.x / SLC, s = blockIdx.x % SLC;
    int tid = threadIdx.x;
    int wave = tid >> 6, lane = tid & 63;
    const float* sb = sc + (size_t)b * NPG;

    for (int i = tid; i < 4 * M_M * H2C; i += 256) ((float*)aa4)[i] = 0.f;

    float lmax = -1e30f;
    for (int n = tid; n < NPG; n += 256) lmax = fmaxf(lmax, sb[n]);
    red[tid] = lmax;
    __syncthreads();
    for (int off = 128; off > 0; off >>= 1) {
        if (tid < off) red[tid] = fmaxf(red[tid], red[tid + off]);
        __syncthreads();
    }
    float mx = red[0];
    __syncthreads();
    float lsum = 0.f;
    for (int n = tid; n < NPG; n += 256) lsum += expf(sb[n] - mx);
    red[tid] = lsum;
    __syncthreads();
    for (int off = 128; off > 0; off >>= 1) {
        if (tid < off) red[tid] += red[tid + off];
        __syncthreads();
    }
    float inv = 1.f / red[0];
    __syncthreads();

    int nbase = s * APB;
    const float* hb = h2 + (size_t)b * NPG * H2C;
    int   lbls[APB / 4];
    float wts[APB / 4];
    float hvs[APB / 4];
    #pragma unroll
    for (int it = 0; it < APB / 4; ++it) {
        int n = nbase + it * 4 + wave;               // wave-uniform
        lbls[it] = labels[b * NPG + n];
        wts[it]  = expf(sb[n] - mx) * inv;
        hvs[it]  = hb[(size_t)n * H2C + lane];       // 256B coalesced per wave
    }
    #pragma unroll
    for (int it = 0; it < APB / 4; ++it) {
        aa4[wave][lbls[it]][lane] += hvs[it] * wts[it];   // identical order
    }
    __syncthreads();
    float* pb = partial + (size_t)(b * SLC + s) * M_M * H2C;
    for (int i = tid; i < M_M * H2C; i += 256) {
        float v = ((float*)aa4)[i] + ((float*)aa4)[M_M * H2C + i]
                + ((float*)aa4)[2 * M_M * H2C + i] + ((float*)aa4)[3 * M_M * H2C + i];
        pb[i] = v;
    }
}

// Reduce SLC partials + concat aa_features + pad + bf16 pack -> x0b.
__global__ __launch_bounds__(256) void x0_finalize(
    const float* __restrict__ partial, const float* __restrict__ aaf,
    short* __restrict__ x0b)
{
    int idx = blockIdx.x * 256 + threadIdx.x;
    if (idx >= B_G * MPAD * KP2) return;
    int b = idx / (MPAD * KP2);
    int rem = idx - b * (MPAD * KP2);
    int m = rem / KP2, k = rem - m * KP2;
    float v = 0.f;
    if (m < M_M) {
        if (k < H2C) {
            const float* pb = partial + (size_t)b * SLC * M_M * H2C + m * H2C + k;
            #pragma unroll
            for (int s = 0; s < SLC; ++s) v += pb[(size_t)s * (M_M * H2C)];
        } else if (k < XDIM) {
            v = aaf[((size_t)b * M_M + m) * AAF + (k - H2C)];
        }
    }
    x0b[idx] = f2bf(v);
}

// ---------------------------------------------------------------------------
// ARMA recurrence, one block per (b,k), 256 threads (R11, verified <41us).
// ---------------------------------------------------------------------------
__global__ __launch_bounds__(256, 1) void arma_iter(
    const short* __restrict__ x0b, const short* __restrict__ Wtb,
    const short* __restrict__ Wab, const float* __restrict__ arma_bias,
    const int* __restrict__ aa_off, const int* __restrict__ aa_src,
    const float* __restrict__ aa_nrm, float* __restrict__ gfull)
{
    __shared__ float Abuf[MPAD][GP];        // 33.8 KB (propagated-state input)
    __shared__ float Rall[3][MPAD][GP];     // 101.4 KB (hoisted root terms)
    __shared__ short Bb16[MPAD][GPS];       // 17.4 KB (bf16 state shadow)
    __shared__ int   s_off[M_M + 1];
    __shared__ int   s_src[EA_E];
    __shared__ float s_nrm[EA_E];
    int b = blockIdx.x / K_ST, k = blockIdx.x % K_ST;
    int tid = threadIdx.x;
    int oi = tid & 15, mi = tid >> 4;       // prop: mi in [0,16), 4 rows each
    int c0 = oi * 4, c1 = 64 + oi * 4;
    int lane = tid & 63, wave = tid >> 6;   // 4 waves
    int l16 = lane & 15, quad = lane >> 4;
    int w2 = wave >> 1, nh = wave & 1;      // wave handles m-tiles {w2, w2+2}

    if (tid < M_M + 1) s_off[tid] = aa_off[tid];
    if (tid < EA_E) { s_src[tid] = aa_src[tid]; s_nrm[tid] = aa_nrm[tid]; }
    for (int i = tid; i < MPAD * GPS / 2; i += 256) {
        ((int*)Bb16)[i] = 0;           // zero bf16 shadow (rows >= M_M stay 0)
    }

    // A-fragments for this wave's 2 m-tiles (32 x0 rows), reused by 7 GEMMs.
    bf16x8 Afr[2][5];
    #pragma unroll
    for (int h = 0; h < 2; ++h) {
        int mt = w2 + 2 * h;
        const short* xb = x0b + (size_t)b * MPAD * KP2 + (mt * 16 + l16) * KP2;
        #pragma unroll
        for (int ks = 0; ks < 5; ++ks)
            Afr[h][ks] = *(const bf16x8*)(xb + ks * 32 + quad * 8);
    }

    // x0 @ Wtb[slice] -> dst in LDS. One shared B-frag set, 2 m-tiles.
    auto x0_gemm = [&](const short* __restrict__ W, float (*dst)[GP]) {
        bf16x8 Bfr[5][4];
        #pragma unroll
        for (int ks = 0; ks < 5; ++ks)
            #pragma unroll
            for (int nt = 0; nt < 4; ++nt)
                Bfr[ks][nt] = *(const bf16x8*)(W +
                    (size_t)((nh * 4 + nt) * 16 + l16) * KP2 + ks * 32 + quad * 8);
        #pragma unroll
        for (int h = 0; h < 2; ++h) {
            int mt = w2 + 2 * h;
            f32x4 acc[4];
            #pragma unroll
            for (int nt = 0; nt < 4; ++nt) acc[nt] = (f32x4){0.f, 0.f, 0.f, 0.f};
            #pragma unroll
            for (int ks = 0; ks < 5; ++ks)
                #pragma unroll
                for (int nt = 0; nt < 4; ++nt)
                    acc[nt] = __builtin_amdgcn_mfma_f32_16x16x32_bf16(
                        Afr[h][ks], Bfr[ks][nt], acc[nt], 0, 0, 0);
            #pragma unroll
            for (int nt = 0; nt < 4; ++nt)
                #pragma unroll
                for (int r = 0; r < 4; ++r)
                    dst[mt * 16 + quad * 4 + r][(nh * 4 + nt) * 16 + l16] = acc[nt][r];
        }
    };

    // prologue: init GEMM -> Abuf; root GEMMs t=0..2 -> Rall[0..2]
    x0_gemm(Wtb + (size_t)k * G_DIM * KP2, Abuf);
    #pragma unroll
    for (int t = 0; t < 3; ++t)
        x0_gemm(Wtb + (size_t)(K_ST + t * K_ST + k) * G_DIM * KP2, Rall[t]);

    float* gb = gfull + ((size_t)(b * K_ST + k)) * M_M * G_DIM;
    __syncthreads();   // Abuf(init) + Rall(0..2) + Bb16(zero) + CSR visible

    #pragma unroll
    for (int t = 0; t < T_L; ++t) {
        if (t > 0) {
            // state GEMM: relu-state (bf16 shadow) @ Wab -> Abuf.
            // Shared W-frag set (16 loads) feeds both m-tiles (32 MFMAs).
            const short* aw = Wab + (size_t)((t - 1) * K_ST + k) * G_DIM * G_DIM;
            bf16x8 Wfr[4][4];
            #pragma unroll
            for (int ks = 0; ks < 4; ++ks)
                #pragma unroll
                for (int nt = 0; nt < 4; ++nt)
                    Wfr[ks][nt] = *(const bf16x8*)(aw +
                        (size_t)((nh * 4 + nt) * 16 + l16) * G_DIM + ks * 32 + quad * 8);
            #pragma unroll
            for (int h = 0; h < 2; ++h) {
                int mt = w2 + 2 * h;
                f32x4 acc[4];
                #pragma unroll
                for (int nt = 0; nt < 4; ++nt) acc[nt] = (f32x4){0.f, 0.f, 0.f, 0.f};
                #pragma unroll
                for (int ks = 0; ks < 4; ++ks) {
                    bf16x8 a = *(const bf16x8*)&Bb16[mt * 16 + l16][ks * 32 + quad * 8];
                    #pragma unroll
                    for (int nt = 0; nt < 4; ++nt)
                        acc[nt] = __builtin_amdgcn_mfma_f32_16x16x32_bf16(
                            a, Wfr[ks][nt], acc[nt], 0, 0, 0);
                }
                #pragma unroll
                for (int nt = 0; nt < 4; ++nt)
                    #pragma unroll
                    for (int r = 0; r < 4; ++r)
                        Abuf[mt * 16 + quad * 4 + r][(nh * 4 + nt) * 16 + l16] = acc[nt][r];
            }
            if (t == 3) {
                // batch root GEMMs t=3..5 into Rall[0..2] (old contents'
                // consumers finished before the end-of-step-2 barrier)
                #pragma unroll
                for (int tt = 3; tt < 6; ++tt)
                    x0_gemm(Wtb + (size_t)(K_ST + tt * K_ST + k) * G_DIM * KP2,
                            Rall[tt - 3]);
            }
            __syncthreads();   // Abuf (+Rall at t==3) complete before prop
        }
        const float (*Rb)[GP] = Rall[t % 3];
        const float* bb = arma_bias + ((size_t)t * K_ST + k) * G_DIM;
        float4 bias0 = *(const float4*)(bb + c0);
        float4 bias1 = *(const float4*)(bb + c1);
        #pragma unroll
        for (int r = 0; r < 4; ++r) {
            int m = mi * 4 + r;
            if (m < M_M) {
                float4 v0 = bias0, v1 = bias1;
                f4add(v0, *(const float4*)&Rb[m][c0]);
                f4add(v1, *(const float4*)&Rb[m][c1]);
                int j0 = s_off[m], j1 = s_off[m + 1];
                for (int j = j0; j < j1; ++j) {
                    float nv = s_nrm[j];
                    const float* ap = &Abuf[s_src[j]][0];
                    f4fma(v0, nv, *(const float4*)(ap + c0));
                    f4fma(v1, nv, *(const float4*)(ap + c1));
                }
                f4relu(v0);
                f4relu(v1);
                unsigned int p0 = cvtpk_bf16(v0.x, v0.y);
                unsigned int p1 = cvtpk_bf16(v0.z, v0.w);
                unsigned int p2 = cvtpk_bf16(v1.x, v1.y);
                unsigned int p3 = cvtpk_bf16(v1.z, v1.w);
                *(uint2*)&Bb16[m][c0] = make_uint2(p0, p1);
                *(uint2*)&Bb16[m][c1] = make_uint2(p2, p3);
                if (t == T_L - 1) {
                    *(float4*)(gb + m * G_DIM + c0) = v0;
                    *(float4*)(gb + m * G_DIM + c1) = v1;
                }
            }
        }
        __syncthreads();   // state complete; Abuf/Rall reads done
    }
}

// ---------------------------------------------------------------------------
// Mean over K, amino attention readout, MLP head. One block per graph.
// ---------------------------------------------------------------------------
__global__ __launch_bounds__(128) void aa_readout_mlp(
    const float* __restrict__ gfull, const float* __restrict__ wa,
    const float* __restrict__ ba,
    const float* __restrict__ W1, const float* __restrict__ b1,
    const float* __restrict__ W2, const float* __restrict__ b2,
    const float* __restrict__ W3, const float* __restrict__ b3,
    const float* __restrict__ W4, const float* __restrict__ b4,
    float* __restrict__ out)
{
    __shared__ float g[M_M][G_DIM + 1];
    __shared__ float s2[M_M];
    __shared__ float p[G_DIM];
    __shared__ float r1[64], r2[32], r3[16];
    int b = blockIdx.x, tid = threadIdx.x;
    const float* g0 = gfull + (size_t)b * K_ST * M_M * G_DIM;
    for (int i = tid; i < M_M * G_DIM; i += 128) {
        int m = i >> 7, o = i & 127;
        g[m][o] = (g0[i] + g0[M_M*G_DIM + i] + g0[2*M_M*G_DIM + i]) * (1.f/3.f);
    }
    __syncthreads();
    if (tid < M_M) {
        float sv = ba[0];
        for (int o = 0; o < G_DIM; ++o) sv += g[tid][o] * wa[o];
        s2[tid] = sv;
    }
    __syncthreads();
    if (tid < 64) {
        float v = (tid < M_M) ? s2[tid] : -1e30f;
        float mx = v;
        #pragma unroll
        for (int d = 32; d > 0; d >>= 1) mx = fmaxf(mx, __shfl_xor(mx, d));
        float e = (tid < M_M) ? expf(s2[tid] - mx) : 0.f;
        float den = e;
        #pragma unroll
        for (int d = 32; d > 0; d >>= 1) den += __shfl_xor(den, d);
        float inv = 1.f / den;
        if (tid < M_M) s2[tid] = e * inv;
    }
    __syncthreads();
    {
        float pv = 0.f;
        for (int m = 0; m < M_M; ++m) pv += g[m][tid] * s2[m];
        p[tid] = pv;
    }
    __syncthreads();
    if (tid < 64) {
        float v = b1[tid];
        for (int i = 0; i < 128; ++i) v += p[i] * W1[i * 64 + tid];
        r1[tid] = fmaxf(v, 0.f);
    }
    __syncthreads();
    if (tid < 32) {
        float v = b2[tid];
        for (int i = 0; i < 64; ++i) v += r1[i] * W2[i * 32 + tid];
        r2[tid] = fmaxf(v, 0.f);
    }
    __syncthreads();
    if (tid < 16) {
        float v = b3[tid];
        for (int i = 0; i < 32; ++i) v += r2[i] * W3[i * 16 + tid];
        r3[tid] = fmaxf(v, 0.f);
    }
    __syncthreads();
    if (tid == 0) {
        float v = b4[0];
        for (int i = 0; i < 16; ++i) v += r3[i] * W4[i];
        out[b] = v;
    }
}

// ---------------------------------------------------------------------------
extern "C" void kernel_launch(void* const* d_in, const int* in_sizes, int n_in,
                              void* d_out, int out_size, void* d_ws, size_t ws_size,
                              hipStream_t stream)
{
    (void)in_sizes; (void)n_in; (void)out_size; (void)ws_size;
    const float* x            = (const float*)d_in[0];
    const float* edge_attr    = (const float*)d_in[1];
    const float* aa_features  = (const float*)d_in[2];
    const int*   edge_index   = (const int*)  d_in[3];
    const int*   mono_labels  = (const int*)  d_in[4];
    const int*   amino_ei     = (const int*)  d_in[5];
    const float* W_e1 = (const float*)d_in[6];
    const float* b_e1 = (const float*)d_in[7];
    const float* root1= (const float*)d_in[8];
    const float* bias1= (const float*)d_in[9];
    const float* W_e2 = (const float*)d_in[10];
    const float* b_e2 = (const float*)d_in[11];
    const float* root2= (const float*)d_in[12];
    const float* bias2= (const float*)d_in[13];
    const float* Wa_atom = (const float*)d_in[14];
    const float* ba_atom = (const float*)d_in[15];
    const float* arma_init_w = (const float*)d_in[16];
    const float* arma_w      = (const float*)d_in[17];
    const float* arma_root_w = (const float*)d_in[18];
    const float* arma_bias   = (const float*)d_in[19];
    const float* Wa_aa = (const float*)d_in[20];
    const float* ba_aa = (const float*)d_in[21];
    const float* W1 = (const float*)d_in[22];
    const float* b1 = (const float*)d_in[23];
    const float* W2 = (const float*)d_in[24];
    const float* b2 = (const float*)d_in[25];
    const float* W3 = (const float*)d_in[26];
    const float* b3 = (const float*)d_in[27];
    const float* W4 = (const float*)d_in[28];
    const float* b4 = (const float*)d_in[29];

    float* ws = (float*)d_ws;
    float* h1    = ws;                                   // N*32
    float* h2    = h1   + (size_t)N_ATOMS * H1C;         // N*64
    float* h_aa  = h2   + (size_t)N_ATOMS * H2C;         // legacy slot, unused
    float* sc    = h_aa + (size_t)B_G * M_M * XDIM;      // B*NPG raw scores
    int*   aa_off = (int*)(sc + (size_t)B_G * NPG);      // M+1
    int*   aa_src = aa_off + (M_M + 1);                  // EA
    float* aa_nrm = (float*)(aa_src + EA_E);             // EA
    int*   deg    = (int*)(aa_nrm + EA_E);               // N+1 (counts)
    int*   cursor = deg + (N_ATOMS + 1);                 // N
    int*   ecnt   = cursor + N_ATOMS;                    // 1 (CSR base counter)
    int*   gcnt   = ecnt + 1;                            // B_G (unused, layout keep)
    int*   ipos   = gcnt + B_G;                          // E (edge -> CSR slot)
    int*   aoff   = ipos + E_EDGES;                      // N (node slot bases)
    float* RC    = (float*)(aoff + N_ATOMS);             // msg/partial arena
    float* gfull = RC + (size_t)B_G * NS * M_M * G_DIM;  // B*3*M*128
    short* Wtb   = (short*)((((uintptr_t)(gfull + (size_t)B_G * K_ST * M_M * G_DIM)) + 15)
                            & ~(uintptr_t)15);           // NS*128*168 bf16 (903 KB)
    short* x0b   = Wtb + (size_t)NS * G_DIM * KP2;       // B*64*168 bf16 (1.07 MB)
    short* Wab   = x0b + (size_t)B_G * MPAD * KP2;       // 15*128*128 bf16 (492 KB)
    short* WB1   = Wab + (size_t)(T_L - 1) * K_ST * G_DIM * G_DIM; // 32*544 bf16
    short* WB2   = WB1 + (size_t)H1C * KW;               // 64*544 bf16
    float* msg   = RC;     // edge messages (dst-sorted)
    float* partial = RC;   // scatter partials (6.4 MB), msg dead by then
    (void)h_aa;

    // zero: deg(N+1) + cursor(N) + ecnt(1) + gcnt(B_G)
    (void)hipMemsetAsync(deg, 0, (2 * N_ATOMS + 2 + B_G) * sizeof(int), stream);

    // all one-time prep (bf16 packs + deg count + amino CSR) in one kernel
    prep_all<<<1 + (PREP_TOTAL + 255) / 256, 256, 0, stream>>>(
        W_e1, b_e1, WB1, W_e2, b_e2, WB2,
        arma_init_w, arma_root_w, Wtb, arma_w, Wab,
        edge_index, deg, amino_ei, aa_off, aa_src, aa_nrm);

    // CSR offsets: single atomic-base kernel (replaces 3-phase scan)
    csr_offsets<<<NSB, 256, 0, stream>>>(deg, ecnt, aoff);

    // conv1 (MFMA): 128 edges/block; computes ipos in-kernel, scatters to slots
    edge_msg_v2<H1C, 2, 2, 8, true><<<(E_EDGES + 127) / 128, 256, 0, stream>>>(
        x, edge_attr, edge_index, ipos, aoff, cursor, WB1, msg);
    gather_update<DIN, H1C, false><<<(N_ATOMS + 7) / 8, 256, 0, stream>>>(
        msg, aoff, deg, x, root1, bias1, h1, nullptr, nullptr, nullptr);
    // conv2 (MFMA): 128 edges/block; gather fused with attention score
    edge_msg_v2<H2C, 4, 1, 8, false><<<(E_EDGES + 127) / 128, 256, 0, stream>>>(
        h1, edge_attr, edge_index, ipos, nullptr, nullptr, WB2, msg);
    gather_update<H1C, H2C, true><<<(N_ATOMS + 3) / 4, 256, 0, stream>>>(
        msg, aoff, deg, h1, root2, bias2, h2, Wa_atom, ba_atom, sc);

    // atom attention readout: scatter with inline softmax -> finalize
    atom_scatter_sm<<<B_G * SLC, 256, 0, stream>>>(h2, sc, mono_labels, partial);
    x0_finalize<<<(B_G * MPAD * KP2 + 255) / 256, 256, 0, stream>>>(
        partial, aa_features, x0b);

    // ARMA: 256-thread blocks (1 wave/SIMD -> 256-VGPR budget, shared B-frags)
    arma_iter<<<B_G * K_ST, 256, 0, stream>>>(x0b, Wtb, Wab, arma_bias,
                                              aa_off, aa_src, aa_nrm, gfull);
    aa_readout_mlp<<<B_G, 128, 0, stream>>>(gfull, Wa_aa, ba_aa, W1, b1, W2, b2, W3, b3, W4, b4,
                                            (float*)d_out);
}